// Round 1
// baseline (2468.510 us; speedup 1.0000x reference)
//
#include <hip/hip_runtime.h>
#include <cstdint>
#include <cstddef>

#define B 16
#define S 1024
#define D 768
#define H 12
#define HD 64
#define NTOK (B * S)        // 16384
#define QKV_N (3 * D)       // 2304
#define SCALE 0.125f        // 64^-0.5

// ---------------- mask normalization (bool-byte vs int32 agnostic) -------------
__global__ __launch_bounds__(256) void normalize_mask_kernel(
    const unsigned char* __restrict__ raw, int* __restrict__ outm, int n) {
    __shared__ int s_isbyte;
    const int tid = threadIdx.x;
    if (tid == 0) s_isbyte = 0;
    __syncthreads();
    int found = 0;
    for (int i = tid; i < n; i += 256) {
        if ((i & 3) != 0 && raw[i] != 0) found = 1;
    }
    if (found) atomicOr(&s_isbyte, 1);
    __syncthreads();
    const int isbyte = s_isbyte;
    if (isbyte) {
        for (int i = tid; i < n; i += 256) outm[i] = raw[i] ? 1 : 0;
    } else {
        const int* r32 = (const int*)raw;
        for (int i = tid; i < n; i += 256) outm[i] = r32[i] ? 1 : 0;
    }
}

// ---------------- fp32 tiled GEMM: out[m,n] = sum_k A[m,k]*W[n,k] + bias[n] ----
// rows with rowmask[m]==0 are zeroed (rowmask may be nullptr)
__global__ __launch_bounds__(256) void gemm_bias_kernel(
    const float* __restrict__ A, const float* __restrict__ W,
    const float* __restrict__ bias, float* __restrict__ out,
    int M, int N, int K, const int* __restrict__ rowmask) {
    __shared__ float As[16][68];
    __shared__ float Ws[16][68];
    const int bm = blockIdx.y * 64;
    const int bn = blockIdx.x * 64;
    const int tid = threadIdx.x;
    const int tm = tid >> 4;    // 0..15
    const int tn = tid & 15;    // 0..15
    const int e = tid * 4;
    const int ml = e >> 4;      // 0..63
    const int kl = e & 15;      // 0,4,8,12

    float acc[4][4] = {};

    for (int kt = 0; kt < K; kt += 16) {
        const float4 a4 = *(const float4*)&A[(size_t)(bm + ml) * K + kt + kl];
        const float4 w4 = *(const float4*)&W[(size_t)(bn + ml) * K + kt + kl];
        __syncthreads();   // WAR: prior iter finished reading LDS
        As[kl + 0][ml] = a4.x; As[kl + 1][ml] = a4.y;
        As[kl + 2][ml] = a4.z; As[kl + 3][ml] = a4.w;
        Ws[kl + 0][ml] = w4.x; Ws[kl + 1][ml] = w4.y;
        Ws[kl + 2][ml] = w4.z; Ws[kl + 3][ml] = w4.w;
        __syncthreads();
#pragma unroll
        for (int k = 0; k < 16; ++k) {
            const float4 av = *(const float4*)&As[k][tm * 4];
            const float4 wv = *(const float4*)&Ws[k][tn * 4];
            const float aa[4] = {av.x, av.y, av.z, av.w};
            const float ww[4] = {wv.x, wv.y, wv.z, wv.w};
#pragma unroll
            for (int i = 0; i < 4; ++i)
#pragma unroll
                for (int j = 0; j < 4; ++j)
                    acc[i][j] += aa[i] * ww[j];
        }
    }

#pragma unroll
    for (int i = 0; i < 4; ++i) {
        const int m = bm + tm * 4 + i;
        const bool mv = rowmask ? (rowmask[m] != 0) : true;
        const int n0 = bn + tn * 4;
        float4 o;
        o.x = mv ? acc[i][0] + bias[n0 + 0] : 0.f;
        o.y = mv ? acc[i][1] + bias[n0 + 1] : 0.f;
        o.z = mv ? acc[i][2] + bias[n0 + 2] : 0.f;
        o.w = mv ? acc[i][3] + bias[n0 + 3] : 0.f;
        *(float4*)&out[(size_t)m * N + n0] = o;
    }
}

// ---------------- flash attention (fp32, online softmax) ----------------------
// qkv layout: [B,S,3,H,HD] flat rows of 2304. 16 q-rows per block, 256 threads.
// thread (r,cc): r = q-row in tile, cc = 0..15; scores for keys cc+16t, dims cc*4..cc*4+3
__global__ __launch_bounds__(256) void attn_kernel(
    const float* __restrict__ qkv, const int* __restrict__ mask,
    float* __restrict__ ctx) {
    __shared__ float ks[64][68];
    __shared__ float vs[64][68];
    __shared__ float ps[16][68];
    __shared__ int kms[64];

    const int blk = blockIdx.x;
    const int qt = blk & 63;             // S/16 = 64 q-tiles
    const int h = (blk >> 6) % H;
    const int b = blk / (64 * H);
    const int tid = threadIdx.x;
    const int r = tid >> 4;              // 0..15
    const int cc = tid & 15;             // 0..15
    const int qrow = qt * 16 + r;

    const size_t qbase = ((size_t)(b * S + qrow)) * QKV_N + h * HD;
    float4 q[16];
#pragma unroll
    for (int x = 0; x < 16; ++x) q[x] = *(const float4*)&qkv[qbase + x * 4];
    const int qvalid = mask[b * S + qrow];

    float m_run = -1e30f, l_run = 0.f;
    float acc[4] = {0.f, 0.f, 0.f, 0.f};

    for (int kt = 0; kt < S; kt += 64) {
        __syncthreads();   // WAR on ks/vs/ps/kms
#pragma unroll
        for (int t = 0; t < 4; ++t) {
            const int e = (tid + t * 256) * 4;   // 0..4092
            const int jj = e >> 6;
            const int hd = e & 63;
            const size_t g = ((size_t)(b * S + kt + jj)) * QKV_N + D + h * HD + hd;
            *(float4*)&ks[jj][hd] = *(const float4*)&qkv[g];        // K
            *(float4*)&vs[jj][hd] = *(const float4*)&qkv[g + D];    // V
        }
        if (tid < 64) kms[tid] = mask[b * S + kt + tid];
        __syncthreads();

        // scores: 4 keys per thread, full 64-dot each
        const int j0 = cc, j1 = cc + 16, j2 = cc + 32, j3 = cc + 48;
        float d0 = 0.f, d1 = 0.f, d2 = 0.f, d3 = 0.f;
#pragma unroll
        for (int x = 0; x < 16; ++x) {
            const float4 k0 = *(const float4*)&ks[j0][x * 4];
            const float4 k1 = *(const float4*)&ks[j1][x * 4];
            const float4 k2 = *(const float4*)&ks[j2][x * 4];
            const float4 k3 = *(const float4*)&ks[j3][x * 4];
            const float4 qq = q[x];
            d0 += qq.x * k0.x + qq.y * k0.y + qq.z * k0.z + qq.w * k0.w;
            d1 += qq.x * k1.x + qq.y * k1.y + qq.z * k1.z + qq.w * k1.w;
            d2 += qq.x * k2.x + qq.y * k2.y + qq.z * k2.z + qq.w * k2.w;
            d3 += qq.x * k3.x + qq.y * k3.y + qq.z * k3.z + qq.w * k3.w;
        }
        const int v0 = kms[j0], v1 = kms[j1], v2 = kms[j2], v3 = kms[j3];
        const float s0 = v0 ? d0 * SCALE : -1e30f;
        const float s1 = v1 ? d1 * SCALE : -1e30f;
        const float s2 = v2 ? d2 * SCALE : -1e30f;
        const float s3 = v3 ? d3 * SCALE : -1e30f;

        float mt = fmaxf(fmaxf(s0, s1), fmaxf(s2, s3));
#pragma unroll
        for (int o = 8; o; o >>= 1) mt = fmaxf(mt, __shfl_xor(mt, o, 16));
        const float m_new = fmaxf(m_run, mt);

        const float p0 = v0 ? expf(s0 - m_new) : 0.f;
        const float p1 = v1 ? expf(s1 - m_new) : 0.f;
        const float p2 = v2 ? expf(s2 - m_new) : 0.f;
        const float p3 = v3 ? expf(s3 - m_new) : 0.f;

        const float scalef = expf(m_run - m_new);  // 0 or 1 in degenerate cases
        float lt = p0 + p1 + p2 + p3;
#pragma unroll
        for (int o = 8; o; o >>= 1) lt += __shfl_xor(lt, o, 16);
        l_run = l_run * scalef + lt;
        m_run = m_new;
        acc[0] *= scalef; acc[1] *= scalef; acc[2] *= scalef; acc[3] *= scalef;

        ps[r][j0] = p0; ps[r][j1] = p1; ps[r][j2] = p2; ps[r][j3] = p3;
        __syncthreads();

        // PV: dims cc*4..cc*4+3
#pragma unroll 8
        for (int jj = 0; jj < 64; ++jj) {
            const float p = ps[r][jj];
            const float4 vv = *(const float4*)&vs[jj][cc * 4];
            acc[0] += p * vv.x; acc[1] += p * vv.y;
            acc[2] += p * vv.z; acc[3] += p * vv.w;
        }
    }

    const float inv = (qvalid && l_run > 0.f) ? 1.f / l_run : 0.f;
    float4 o4;
    o4.x = acc[0] * inv; o4.y = acc[1] * inv;
    o4.z = acc[2] * inv; o4.w = acc[3] * inv;
    *(float4*)&ctx[((size_t)(b * S + qrow)) * D + h * HD + cc * 4] = o4;
}

// -------------------------------------------------------------------------------
extern "C" void kernel_launch(void* const* d_in, const int* in_sizes, int n_in,
                              void* d_out, int out_size, void* d_ws, size_t ws_size,
                              hipStream_t stream) {
    const float* hidden = (const float*)d_in[0];
    const unsigned char* maskraw = (const unsigned char*)d_in[1];
    const float* qkv_w = (const float*)d_in[2];
    const float* qkv_b = (const float*)d_in[3];
    const float* proj_w = (const float*)d_in[4];
    const float* proj_b = (const float*)d_in[5];
    float* out = (float*)d_out;

    char* ws = (char*)d_ws;
    int* maskN = (int*)ws;                                   // 64 KB
    float* qkvbuf = (float*)(ws + 65536);                    // 16384*2304 f32
    float* ctxbuf = qkvbuf + (size_t)NTOK * QKV_N;           // 16384*768 f32

    normalize_mask_kernel<<<1, 256, 0, stream>>>(maskraw, maskN, NTOK);

    dim3 g1(QKV_N / 64, NTOK / 64);   // (36, 256)
    gemm_bias_kernel<<<g1, 256, 0, stream>>>(hidden, qkv_w, qkv_b, qkvbuf,
                                             NTOK, QKV_N, D, nullptr);

    attn_kernel<<<dim3(B * H * (S / 16)), 256, 0, stream>>>(qkvbuf, maskN, ctxbuf);

    dim3 g2(D / 64, NTOK / 64);       // (12, 256)
    gemm_bias_kernel<<<g2, 256, 0, stream>>>(ctxbuf, proj_w, proj_b, out,
                                             NTOK, D, D, maskN);
}

// Round 2
// 535.918 us; speedup vs baseline: 4.6061x; 4.6061x over previous
//
#include <hip/hip_runtime.h>
#include <cstdint>
#include <cstddef>

#define B 16
#define S 1024
#define D 768
#define H 12
#define HD 64
#define NTOK (B * S)        // 16384
#define QKV_N (3 * D)       // 2304
#define SCALE 0.125f        // 64^-0.5

typedef _Float16 f16x8 __attribute__((ext_vector_type(8)));
typedef _Float16 f16x4 __attribute__((ext_vector_type(4)));
typedef float f32x4 __attribute__((ext_vector_type(4)));

// ---------------- mask normalization (bool-byte vs int32 agnostic) -------------
__global__ __launch_bounds__(256) void normalize_mask_kernel(
    const unsigned char* __restrict__ raw, int* __restrict__ outm, int n) {
    __shared__ int s_isbyte;
    const int tid = threadIdx.x;
    if (tid == 0) s_isbyte = 0;
    __syncthreads();
    int found = 0;
    for (int i = tid; i < n; i += 256) {
        if ((i & 3) != 0 && raw[i] != 0) found = 1;
    }
    if (found) atomicOr(&s_isbyte, 1);
    __syncthreads();
    const int isbyte = s_isbyte;
    if (isbyte) {
        for (int i = tid; i < n; i += 256) outm[i] = raw[i] ? 1 : 0;
    } else {
        const int* r32 = (const int*)raw;
        for (int i = tid; i < n; i += 256) outm[i] = r32[i] ? 1 : 0;
    }
}

// ---------------- f32 -> f16 conversion ----------------------------------------
__global__ __launch_bounds__(256) void cvt_f32_f16(
    const float* __restrict__ in, _Float16* __restrict__ out, int n4) {
    const int i = blockIdx.x * 256 + threadIdx.x;
    if (i < n4) {
        const float4 v = ((const float4*)in)[i];
        f16x4 o;
        o[0] = (_Float16)v.x; o[1] = (_Float16)v.y;
        o[2] = (_Float16)v.z; o[3] = (_Float16)v.w;
        ((f16x4*)out)[i] = o;
    }
}

// ---------------- f16 MFMA GEMM: C[m,n] = sum_k A[m,k]*W[n,k] + bias[n] --------
// 128x128 tile, 256 threads = 4 waves (2x2 of 64x64), K-step 32.
// MODE 0: write f32 out with rowmask zeroing.
// MODE 1: scatter f16 into q[B,H,S,64], k[B,H,S,64], vt[B,H,64,S].
template <int MODE>
__global__ __launch_bounds__(256) void gemm16(
    const _Float16* __restrict__ A, const _Float16* __restrict__ Wm,
    const float* __restrict__ bias, const int* __restrict__ rowmask,
    int K, int N, float* __restrict__ outf,
    _Float16* __restrict__ qb, _Float16* __restrict__ kb,
    _Float16* __restrict__ vtb) {
    __shared__ _Float16 As[128][40];
    __shared__ _Float16 Bs[128][40];
    const int bm = blockIdx.y * 128;
    const int bn = blockIdx.x * 128;
    const int tid = threadIdx.x;
    const int w = tid >> 6, lane = tid & 63;
    const int wm = (w >> 1) * 64, wn = (w & 1) * 64;
    const int lg = lane >> 4, lc = lane & 15;
    const int r0 = tid >> 2;            // 0..63
    const int c0 = (tid & 3) * 8;       // 0,8,16,24

    f32x4 acc[4][4] = {};
    f16x8 pa0, pa1, pb0, pb1;
    pa0 = *(const f16x8*)(A + (size_t)(bm + r0) * K + c0);
    pa1 = *(const f16x8*)(A + (size_t)(bm + 64 + r0) * K + c0);
    pb0 = *(const f16x8*)(Wm + (size_t)(bn + r0) * K + c0);
    pb1 = *(const f16x8*)(Wm + (size_t)(bn + 64 + r0) * K + c0);

    for (int kt = 0; kt < K; kt += 32) {
        __syncthreads();
        *(f16x8*)&As[r0][c0] = pa0;
        *(f16x8*)&As[64 + r0][c0] = pa1;
        *(f16x8*)&Bs[r0][c0] = pb0;
        *(f16x8*)&Bs[64 + r0][c0] = pb1;
        __syncthreads();
        if (kt + 32 < K) {
            pa0 = *(const f16x8*)(A + (size_t)(bm + r0) * K + kt + 32 + c0);
            pa1 = *(const f16x8*)(A + (size_t)(bm + 64 + r0) * K + kt + 32 + c0);
            pb0 = *(const f16x8*)(Wm + (size_t)(bn + r0) * K + kt + 32 + c0);
            pb1 = *(const f16x8*)(Wm + (size_t)(bn + 64 + r0) * K + kt + 32 + c0);
        }
        f16x8 af[4], bf[4];
#pragma unroll
        for (int mi = 0; mi < 4; ++mi)
            af[mi] = *(const f16x8*)&As[wm + mi * 16 + lc][lg * 8];
#pragma unroll
        for (int ni = 0; ni < 4; ++ni)
            bf[ni] = *(const f16x8*)&Bs[wn + ni * 16 + lc][lg * 8];
#pragma unroll
        for (int mi = 0; mi < 4; ++mi)
#pragma unroll
            for (int ni = 0; ni < 4; ++ni)
                acc[mi][ni] = __builtin_amdgcn_mfma_f32_16x16x32_f16(
                    af[mi], bf[ni], acc[mi][ni], 0, 0, 0);
    }

    if (MODE == 0) {
#pragma unroll
        for (int mi = 0; mi < 4; ++mi) {
#pragma unroll
            for (int j = 0; j < 4; ++j) {
                const int m = bm + wm + mi * 16 + lg * 4 + j;
                const int mv = rowmask[m];
#pragma unroll
                for (int ni = 0; ni < 4; ++ni) {
                    const int col = bn + wn + ni * 16 + lc;
                    outf[(size_t)m * N + col] =
                        mv ? acc[mi][ni][j] + bias[col] : 0.f;
                }
            }
        }
    } else {
#pragma unroll
        for (int ni = 0; ni < 4; ++ni) {
            const int col = bn + wn + ni * 16 + lc;
            const int which = col / 768;
            const int rem = col - which * 768;
            const int hh = rem >> 6, hd = rem & 63;
            const float bs = bias[col];
            const size_t hb = (size_t)hh;
#pragma unroll
            for (int mi = 0; mi < 4; ++mi) {
#pragma unroll
                for (int j = 0; j < 4; ++j) {
                    const int m = bm + wm + mi * 16 + lg * 4 + j;
                    const int b_ = m >> 10, s_ = m & 1023;
                    const _Float16 val = (_Float16)(acc[mi][ni][j] + bs);
                    const size_t bhh = (size_t)(b_ * H) + hb;
                    if (which == 0)
                        qb[(bhh * S + s_) * HD + hd] = val;
                    else if (which == 1)
                        kb[(bhh * S + s_) * HD + hd] = val;
                    else
                        vtb[(bhh * HD + hd) * S + s_] = val;
                }
            }
        }
    }
}

// ---------------- flash attention, f16 MFMA ------------------------------------
// grid: B*H*(S/64); block 256 = 4 waves; wave w owns q-rows [qt*64+w*16, +16).
// k-tiles of 32 keys; K,Vt frags read direct from global (L2-resident).
__global__ __launch_bounds__(256) void attn_kernel(
    const _Float16* __restrict__ qb, const _Float16* __restrict__ kb,
    const _Float16* __restrict__ vtb, const int* __restrict__ mask,
    _Float16* __restrict__ ctx) {
    __shared__ int km[S];
    __shared__ _Float16 pl[4][16][40];

    const int blk = blockIdx.x;
    const int qt = blk & 15;
    const int h = (blk >> 4) % H;
    const int b = blk / (16 * H);
    const int tid = threadIdx.x;
    const int w = tid >> 6, lane = tid & 63;
    const int lg = lane >> 4, lc = lane & 15;

    for (int i = tid; i < S; i += 256) km[i] = mask[b * S + i];

    const size_t bh = (size_t)(b * H + h);
    const _Float16* Kp = kb + bh * S * HD;
    const _Float16* Vt = vtb + bh * HD * S;

    const int qrow_frag = qt * 64 + w * 16 + lc;
    const _Float16* Qp = qb + (bh * S + qrow_frag) * HD;
    f16x8 qf0 = *(const f16x8*)(Qp + lg * 8);
    f16x8 qf1 = *(const f16x8*)(Qp + 32 + lg * 8);

    __syncthreads();

    float m_run[4], l_run[4];
    f32x4 acc[4] = {};
#pragma unroll
    for (int j = 0; j < 4; ++j) { m_run[j] = -1e30f; l_run[j] = 0.f; }

    for (int kt = 0; kt < S; kt += 32) {
        // QK^T: 16q x 32k, contraction over HD=64 (2 MFMA-K chunks)
        f32x4 cs0 = {}, cs1 = {};
        {
            const f16x8 kf00 = *(const f16x8*)(Kp + (size_t)(kt + lc) * HD + lg * 8);
            const f16x8 kf01 = *(const f16x8*)(Kp + (size_t)(kt + lc) * HD + 32 + lg * 8);
            const f16x8 kf10 = *(const f16x8*)(Kp + (size_t)(kt + 16 + lc) * HD + lg * 8);
            const f16x8 kf11 = *(const f16x8*)(Kp + (size_t)(kt + 16 + lc) * HD + 32 + lg * 8);
            cs0 = __builtin_amdgcn_mfma_f32_16x16x32_f16(qf0, kf00, cs0, 0, 0, 0);
            cs0 = __builtin_amdgcn_mfma_f32_16x16x32_f16(qf1, kf01, cs0, 0, 0, 0);
            cs1 = __builtin_amdgcn_mfma_f32_16x16x32_f16(qf0, kf10, cs1, 0, 0, 0);
            cs1 = __builtin_amdgcn_mfma_f32_16x16x32_f16(qf1, kf11, cs1, 0, 0, 0);
        }
        const int v0 = km[kt + lc];
        const int v1 = km[kt + 16 + lc];

#pragma unroll
        for (int j = 0; j < 4; ++j) {
            const float s0 = v0 ? cs0[j] * SCALE : -1e30f;
            const float s1 = v1 ? cs1[j] * SCALE : -1e30f;
            float mt = fmaxf(s0, s1);
            mt = fmaxf(mt, __shfl_xor(mt, 1));
            mt = fmaxf(mt, __shfl_xor(mt, 2));
            mt = fmaxf(mt, __shfl_xor(mt, 4));
            mt = fmaxf(mt, __shfl_xor(mt, 8));
            const float mn = fmaxf(m_run[j], mt);
            const float p0 = v0 ? __expf(s0 - mn) : 0.f;
            const float p1 = v1 ? __expf(s1 - mn) : 0.f;
            const float sc = __expf(m_run[j] - mn);
            float lt = p0 + p1;
            lt += __shfl_xor(lt, 1);
            lt += __shfl_xor(lt, 2);
            lt += __shfl_xor(lt, 4);
            lt += __shfl_xor(lt, 8);
            l_run[j] = l_run[j] * sc + lt;
            m_run[j] = mn;
            acc[0][j] *= sc; acc[1][j] *= sc;
            acc[2][j] *= sc; acc[3][j] *= sc;
            pl[w][lg * 4 + j][lc] = (_Float16)p0;
            pl[w][lg * 4 + j][16 + lc] = (_Float16)p1;
        }

        // PV: P[16x32] (per-wave LDS) x V[32x64] (Vt global, contiguous frags)
        const f16x8 pf = *(const f16x8*)&pl[w][lc][lg * 8];
#pragma unroll
        for (int t = 0; t < 4; ++t) {
            const f16x8 vf =
                *(const f16x8*)(Vt + (size_t)(lc + 16 * t) * S + kt + lg * 8);
            acc[t] = __builtin_amdgcn_mfma_f32_16x16x32_f16(pf, vf, acc[t], 0, 0, 0);
        }
    }

#pragma unroll
    for (int j = 0; j < 4; ++j) {
        const int qr = qt * 64 + w * 16 + lg * 4 + j;
        const int qv = km[qr];
        const float inv = (qv && l_run[j] > 0.f) ? 1.f / l_run[j] : 0.f;
        const size_t o = ((size_t)(b * S + qr)) * D + h * HD;
#pragma unroll
        for (int t = 0; t < 4; ++t)
            ctx[o + 16 * t + lc] = (_Float16)(acc[t][j] * inv);
    }
}

// -------------------------------------------------------------------------------
extern "C" void kernel_launch(void* const* d_in, const int* in_sizes, int n_in,
                              void* d_out, int out_size, void* d_ws, size_t ws_size,
                              hipStream_t stream) {
    const float* hidden = (const float*)d_in[0];
    const unsigned char* maskraw = (const unsigned char*)d_in[1];
    const float* qkv_w = (const float*)d_in[2];
    const float* qkv_b = (const float*)d_in[3];
    const float* proj_w = (const float*)d_in[4];
    const float* proj_b = (const float*)d_in[5];
    float* out = (float*)d_out;

    char* ws = (char*)d_ws;
    size_t off = 0;
    int* maskN = (int*)(ws + off);          off += (size_t)NTOK * 4;
    _Float16* hid16 = (_Float16*)(ws + off); off += (size_t)NTOK * D * 2;
    _Float16* qkvw16 = (_Float16*)(ws + off); off += (size_t)QKV_N * D * 2;
    _Float16* projw16 = (_Float16*)(ws + off); off += (size_t)D * D * 2;
    _Float16* qb = (_Float16*)(ws + off);   off += (size_t)NTOK * D * 2;
    _Float16* kbuf = (_Float16*)(ws + off); off += (size_t)NTOK * D * 2;
    _Float16* vtb = (_Float16*)(ws + off);  off += (size_t)NTOK * D * 2;
    _Float16* ctx16 = (_Float16*)(ws + off); off += (size_t)NTOK * D * 2;

    normalize_mask_kernel<<<1, 256, 0, stream>>>(maskraw, maskN, NTOK);

    cvt_f32_f16<<<(NTOK * D / 4 + 255) / 256, 256, 0, stream>>>(hidden, hid16, NTOK * D / 4);
    cvt_f32_f16<<<(QKV_N * D / 4 + 255) / 256, 256, 0, stream>>>(qkv_w, qkvw16, QKV_N * D / 4);
    cvt_f32_f16<<<(D * D / 4 + 255) / 256, 256, 0, stream>>>(proj_w, projw16, D * D / 4);

    dim3 g1(QKV_N / 128, NTOK / 128);   // (18, 128)
    gemm16<1><<<g1, 256, 0, stream>>>(hid16, qkvw16, qkv_b, nullptr,
                                      D, QKV_N, nullptr, qb, kbuf, vtb);

    attn_kernel<<<dim3(B * H * (S / 64)), 256, 0, stream>>>(qb, kbuf, vtb, maskN, ctx16);

    dim3 g2(D / 128, NTOK / 128);       // (6, 128)
    gemm16<0><<<g2, 256, 0, stream>>>(ctx16, projw16, proj_b, maskN,
                                      D, D, out, nullptr, nullptr, nullptr);
}

// Round 3
// 293.210 us; speedup vs baseline: 8.4189x; 1.8278x over previous
//
#include <hip/hip_runtime.h>
#include <cstdint>
#include <cstddef>

#define B 16
#define S 1024
#define D 768
#define H 12
#define HD 64
#define NTOK (B * S)        // 16384
#define QKV_N (3 * D)       // 2304
#define SCALE 0.125f        // 64^-0.5
#define C2 2.88539008f      // 2.0 * log2(e): fixed softmax shift (nat-log C=2)

typedef _Float16 f16x8 __attribute__((ext_vector_type(8)));
typedef _Float16 f16x4 __attribute__((ext_vector_type(4)));
typedef float f32x4 __attribute__((ext_vector_type(4)));

#if defined(__has_builtin)
#if __has_builtin(__builtin_amdgcn_exp2f)
#define EXP2(x) __builtin_amdgcn_exp2f(x)
#else
#define EXP2(x) exp2f(x)
#endif
#else
#define EXP2(x) exp2f(x)
#endif

// ---------------- mask normalization (bool-byte vs int32 agnostic) -------------
__global__ __launch_bounds__(256) void normalize_mask_kernel(
    const unsigned char* __restrict__ raw, int* __restrict__ outm, int n) {
    __shared__ int s_isbyte;
    const int tid = threadIdx.x;
    if (tid == 0) s_isbyte = 0;
    __syncthreads();
    int found = 0;
    for (int i = tid; i < n; i += 256) {
        if ((i & 3) != 0 && raw[i] != 0) found = 1;
    }
    if (found) atomicOr(&s_isbyte, 1);
    __syncthreads();
    const int isbyte = s_isbyte;
    if (isbyte) {
        for (int i = tid; i < n; i += 256) outm[i] = raw[i] ? 1 : 0;
    } else {
        const int* r32 = (const int*)raw;
        for (int i = tid; i < n; i += 256) outm[i] = r32[i] ? 1 : 0;
    }
}

// ---------------- f32 -> f16 conversion ----------------------------------------
__global__ __launch_bounds__(256) void cvt_f32_f16(
    const float* __restrict__ in, _Float16* __restrict__ out, int n4) {
    const int i = blockIdx.x * 256 + threadIdx.x;
    if (i < n4) {
        const float4 v = ((const float4*)in)[i];
        f16x4 o;
        o[0] = (_Float16)v.x; o[1] = (_Float16)v.y;
        o[2] = (_Float16)v.z; o[3] = (_Float16)v.w;
        ((f16x4*)out)[i] = o;
    }
}

// ---------------- f16 MFMA GEMM: C[m,n] = sum_k A[m,k]*W[n,k] + bias[n] --------
// 128x128 tile, 256 threads = 4 waves (2x2 of 64x64), K-step 32.
// MODE 0: write f32 out with rowmask zeroing.
// MODE 1: scatter f16 into q[B,H,S,64], k[B,H,S,64], vt[B,H,64,S].
template <int MODE>
__global__ __launch_bounds__(256) void gemm16(
    const _Float16* __restrict__ A, const _Float16* __restrict__ Wm,
    const float* __restrict__ bias, const int* __restrict__ rowmask,
    int K, int N, float* __restrict__ outf,
    _Float16* __restrict__ qb, _Float16* __restrict__ kb,
    _Float16* __restrict__ vtb) {
    __shared__ _Float16 As[128][40];
    __shared__ _Float16 Bs[128][40];
    const int bm = blockIdx.y * 128;
    const int bn = blockIdx.x * 128;
    const int tid = threadIdx.x;
    const int w = tid >> 6, lane = tid & 63;
    const int wm = (w >> 1) * 64, wn = (w & 1) * 64;
    const int lg = lane >> 4, lc = lane & 15;
    const int r0 = tid >> 2;            // 0..63
    const int c0 = (tid & 3) * 8;       // 0,8,16,24

    f32x4 acc[4][4] = {};
    f16x8 pa0, pa1, pb0, pb1;
    pa0 = *(const f16x8*)(A + (size_t)(bm + r0) * K + c0);
    pa1 = *(const f16x8*)(A + (size_t)(bm + 64 + r0) * K + c0);
    pb0 = *(const f16x8*)(Wm + (size_t)(bn + r0) * K + c0);
    pb1 = *(const f16x8*)(Wm + (size_t)(bn + 64 + r0) * K + c0);

    for (int kt = 0; kt < K; kt += 32) {
        __syncthreads();
        *(f16x8*)&As[r0][c0] = pa0;
        *(f16x8*)&As[64 + r0][c0] = pa1;
        *(f16x8*)&Bs[r0][c0] = pb0;
        *(f16x8*)&Bs[64 + r0][c0] = pb1;
        __syncthreads();
        if (kt + 32 < K) {
            pa0 = *(const f16x8*)(A + (size_t)(bm + r0) * K + kt + 32 + c0);
            pa1 = *(const f16x8*)(A + (size_t)(bm + 64 + r0) * K + kt + 32 + c0);
            pb0 = *(const f16x8*)(Wm + (size_t)(bn + r0) * K + kt + 32 + c0);
            pb1 = *(const f16x8*)(Wm + (size_t)(bn + 64 + r0) * K + kt + 32 + c0);
        }
        f16x8 af[4], bf[4];
#pragma unroll
        for (int mi = 0; mi < 4; ++mi)
            af[mi] = *(const f16x8*)&As[wm + mi * 16 + lc][lg * 8];
#pragma unroll
        for (int ni = 0; ni < 4; ++ni)
            bf[ni] = *(const f16x8*)&Bs[wn + ni * 16 + lc][lg * 8];
#pragma unroll
        for (int mi = 0; mi < 4; ++mi)
#pragma unroll
            for (int ni = 0; ni < 4; ++ni)
                acc[mi][ni] = __builtin_amdgcn_mfma_f32_16x16x32_f16(
                    af[mi], bf[ni], acc[mi][ni], 0, 0, 0);
    }

    if (MODE == 0) {
#pragma unroll
        for (int mi = 0; mi < 4; ++mi) {
#pragma unroll
            for (int j = 0; j < 4; ++j) {
                const int m = bm + wm + mi * 16 + lg * 4 + j;
                const int mv = rowmask[m];
#pragma unroll
                for (int ni = 0; ni < 4; ++ni) {
                    const int col = bn + wn + ni * 16 + lc;
                    outf[(size_t)m * N + col] =
                        mv ? acc[mi][ni][j] + bias[col] : 0.f;
                }
            }
        }
    } else {
#pragma unroll
        for (int ni = 0; ni < 4; ++ni) {
            const int col = bn + wn + ni * 16 + lc;
            const int which = col / 768;
            const int rem = col - which * 768;
            const int hh = rem >> 6, hd = rem & 63;
            const float bs = bias[col];
            const size_t hb = (size_t)hh;
#pragma unroll
            for (int mi = 0; mi < 4; ++mi) {
#pragma unroll
                for (int j = 0; j < 4; ++j) {
                    const int m = bm + wm + mi * 16 + lg * 4 + j;
                    const int b_ = m >> 10, s_ = m & 1023;
                    const _Float16 val = (_Float16)(acc[mi][ni][j] + bs);
                    const size_t bhh = (size_t)(b_ * H) + hb;
                    if (which == 0)
                        qb[(bhh * S + s_) * HD + hd] = val;
                    else if (which == 1)
                        kb[(bhh * S + s_) * HD + hd] = val;
                    else
                        vtb[(bhh * HD + hd) * S + s_] = val;
                }
            }
        }
    }
}

// ---------------- flash attention, f16 MFMA, fixed-max softmax -----------------
// grid: B*H*(S/64); block 256 = 4 waves; wave w owns q-rows [qt*64+w*16, +16).
// 64-key tiles; K,Vt staged in LDS (shared by 4 waves) with async-stage split.
__global__ __launch_bounds__(256) void attn_kernel(
    const _Float16* __restrict__ qb, const _Float16* __restrict__ kb,
    const _Float16* __restrict__ vtb, const int* __restrict__ mask,
    _Float16* __restrict__ ctx) {
    __shared__ _Float16 ksm[64][72];   // [key][hd], padded
    __shared__ _Float16 vsm[64][72];   // [hd-d][key], padded (from Vt)
    __shared__ _Float16 pl[4][16][72]; // per-wave P: [q-row][key]
    __shared__ int kml[64];

    const int blk = blockIdx.x;
    const int qt = blk & 15;
    const int h = (blk >> 4) % H;
    const int b = blk / (16 * H);
    const int tid = threadIdx.x;
    const int w = tid >> 6, lane = tid & 63;
    const int lg = lane >> 4, lc = lane & 15;

    const size_t bh = (size_t)(b * H + h);
    const _Float16* Kp = kb + bh * S * HD;
    const _Float16* Vt = vtb + bh * HD * S;
    const int* mrow = mask + b * S;

    const int srow = tid >> 3;          // 0..31
    const int scol = (tid & 7) * 8;     // 0,8,..,56

    // Q fragment (A-frag row = lc), pre-scaled by SCALE*log2(e)
    const int qrow_frag = qt * 64 + w * 16 + lc;
    const _Float16* Qp = qb + (bh * S + qrow_frag) * HD;
    f16x8 qf0 = *(const f16x8*)(Qp + lg * 8);
    f16x8 qf1 = *(const f16x8*)(Qp + 32 + lg * 8);
    const _Float16 qs = (_Float16)(0.125f * 1.44269504f);
    qf0 *= qs; qf1 *= qs;

    // prologue: stage tile 0
    *(f16x8*)&ksm[srow][scol]      = *(const f16x8*)(Kp + (size_t)srow * HD + scol);
    *(f16x8*)&ksm[32 + srow][scol] = *(const f16x8*)(Kp + (size_t)(32 + srow) * HD + scol);
    *(f16x8*)&vsm[srow][scol]      = *(const f16x8*)(Vt + (size_t)srow * S + scol);
    *(f16x8*)&vsm[32 + srow][scol] = *(const f16x8*)(Vt + (size_t)(32 + srow) * S + scol);
    if (tid < 64) kml[tid] = mrow[tid];
    __syncthreads();

    f32x4 acc[4] = {};
    float l_part[4] = {0.f, 0.f, 0.f, 0.f};

    for (int it = 0; it < S / 64; ++it) {
        const int ktn = (it + 1) * 64;
        const bool pref = (it + 1 < S / 64);
        f16x8 gk0, gk1, gv0, gv1;
        int kmn = 0;
        if (pref) {  // issue next tile's loads early (hide under compute)
            gk0 = *(const f16x8*)(Kp + (size_t)(ktn + srow) * HD + scol);
            gk1 = *(const f16x8*)(Kp + (size_t)(ktn + 32 + srow) * HD + scol);
            gv0 = *(const f16x8*)(Vt + (size_t)srow * S + ktn + scol);
            gv1 = *(const f16x8*)(Vt + (size_t)(32 + srow) * S + ktn + scol);
            if (tid < 64) kmn = mrow[ktn + tid];
        }

        // QK^T: 16q x 64k (K=64 contraction via 2 MFMA per key-group)
        f32x4 cs[4];
#pragma unroll
        for (int t = 0; t < 4; ++t) {
            const f16x8 kfa = *(const f16x8*)&ksm[t * 16 + lc][lg * 8];
            const f16x8 kfb = *(const f16x8*)&ksm[t * 16 + lc][32 + lg * 8];
            f32x4 c = {};
            c = __builtin_amdgcn_mfma_f32_16x16x32_f16(qf0, kfa, c, 0, 0, 0);
            c = __builtin_amdgcn_mfma_f32_16x16x32_f16(qf1, kfb, c, 0, 0, 0);
            cs[t] = c;
        }

        // fixed-max softmax: p = exp2(qk*SCALE*log2e - C2); lane-local l sums
#pragma unroll
        for (int t = 0; t < 4; ++t) {
            const int kv = kml[t * 16 + lc];
#pragma unroll
            for (int j = 0; j < 4; ++j) {
                const float p = kv ? EXP2(cs[t][j] - C2) : 0.f;
                l_part[j] += p;
                pl[w][lg * 4 + j][t * 16 + lc] = (_Float16)p;
            }
        }

        // PV: P[16x64] x V^T-frags (contraction over keys, 2 chunks of 32)
        const f16x8 pf0 = *(const f16x8*)&pl[w][lc][lg * 8];
        const f16x8 pf1 = *(const f16x8*)&pl[w][lc][32 + lg * 8];
#pragma unroll
        for (int t = 0; t < 4; ++t) {
            const f16x8 vfa = *(const f16x8*)&vsm[t * 16 + lc][lg * 8];
            const f16x8 vfb = *(const f16x8*)&vsm[t * 16 + lc][32 + lg * 8];
            acc[t] = __builtin_amdgcn_mfma_f32_16x16x32_f16(pf0, vfa, acc[t], 0, 0, 0);
            acc[t] = __builtin_amdgcn_mfma_f32_16x16x32_f16(pf1, vfb, acc[t], 0, 0, 0);
        }

        __syncthreads();   // all waves done reading ksm/vsm
        if (pref) {
            *(f16x8*)&ksm[srow][scol] = gk0;
            *(f16x8*)&ksm[32 + srow][scol] = gk1;
            *(f16x8*)&vsm[srow][scol] = gv0;
            *(f16x8*)&vsm[32 + srow][scol] = gv1;
            if (tid < 64) kml[tid] = kmn;
            __syncthreads();
        }
    }

    // epilogue: reduce l across the 16 key-lanes, normalize, write
#pragma unroll
    for (int j = 0; j < 4; ++j) {
        float l = l_part[j];
        l += __shfl_xor(l, 1);
        l += __shfl_xor(l, 2);
        l += __shfl_xor(l, 4);
        l += __shfl_xor(l, 8);
        const int qr = qt * 64 + w * 16 + lg * 4 + j;
        const int qv = mrow[qr];
        const float inv = (qv && l > 0.f) ? 1.f / l : 0.f;
        const size_t o = ((size_t)(b * S + qr)) * D + h * HD;
#pragma unroll
        for (int t = 0; t < 4; ++t)
            ctx[o + 16 * t + lc] = (_Float16)(acc[t][j] * inv);
    }
}

// -------------------------------------------------------------------------------
extern "C" void kernel_launch(void* const* d_in, const int* in_sizes, int n_in,
                              void* d_out, int out_size, void* d_ws, size_t ws_size,
                              hipStream_t stream) {
    const float* hidden = (const float*)d_in[0];
    const unsigned char* maskraw = (const unsigned char*)d_in[1];
    const float* qkv_w = (const float*)d_in[2];
    const float* qkv_b = (const float*)d_in[3];
    const float* proj_w = (const float*)d_in[4];
    const float* proj_b = (const float*)d_in[5];
    float* out = (float*)d_out;

    char* ws = (char*)d_ws;
    size_t off = 0;
    int* maskN = (int*)(ws + off);          off += (size_t)NTOK * 4;
    _Float16* hid16 = (_Float16*)(ws + off); off += (size_t)NTOK * D * 2;
    _Float16* qkvw16 = (_Float16*)(ws + off); off += (size_t)QKV_N * D * 2;
    _Float16* projw16 = (_Float16*)(ws + off); off += (size_t)D * D * 2;
    _Float16* qb = (_Float16*)(ws + off);   off += (size_t)NTOK * D * 2;
    _Float16* kbuf = (_Float16*)(ws + off); off += (size_t)NTOK * D * 2;
    _Float16* vtb = (_Float16*)(ws + off);  off += (size_t)NTOK * D * 2;
    _Float16* ctx16 = (_Float16*)(ws + off); off += (size_t)NTOK * D * 2;

    normalize_mask_kernel<<<1, 256, 0, stream>>>(maskraw, maskN, NTOK);

    cvt_f32_f16<<<(NTOK * D / 4 + 255) / 256, 256, 0, stream>>>(hidden, hid16, NTOK * D / 4);
    cvt_f32_f16<<<(QKV_N * D / 4 + 255) / 256, 256, 0, stream>>>(qkv_w, qkvw16, QKV_N * D / 4);
    cvt_f32_f16<<<(D * D / 4 + 255) / 256, 256, 0, stream>>>(proj_w, projw16, D * D / 4);

    dim3 g1(QKV_N / 128, NTOK / 128);   // (18, 128)
    gemm16<1><<<g1, 256, 0, stream>>>(hid16, qkvw16, qkv_b, nullptr,
                                      D, QKV_N, nullptr, qb, kbuf, vtb);

    attn_kernel<<<dim3(B * H * (S / 64)), 256, 0, stream>>>(qb, kbuf, vtb, maskN, ctx16);

    dim3 g2(D / 128, NTOK / 128);       // (6, 128)
    gemm16<0><<<g2, 256, 0, stream>>>(ctx16, projw16, proj_b, maskN,
                                      D, D, out, nullptr, nullptr, nullptr);
}

// Round 4
// 289.842 us; speedup vs baseline: 8.5168x; 1.0116x over previous
//
#include <hip/hip_runtime.h>
#include <cstdint>
#include <cstddef>

#define B 16
#define S 1024
#define D 768
#define H 12
#define HD 64
#define NTOK (B * S)        // 16384
#define QKV_N (3 * D)       // 2304
#define SCALE 0.125f        // 64^-0.5
#define C2 2.88539008f      // 2.0 * log2(e): fixed softmax shift (nat-log C=2)

typedef _Float16 f16x8 __attribute__((ext_vector_type(8)));
typedef _Float16 f16x4 __attribute__((ext_vector_type(4)));
typedef float f32x4 __attribute__((ext_vector_type(4)));

typedef __attribute__((address_space(3))) void as3_void;
typedef const __attribute__((address_space(1))) void as1_void;

#if defined(__has_builtin)
#if __has_builtin(__builtin_amdgcn_exp2f)
#define EXP2(x) __builtin_amdgcn_exp2f(x)
#else
#define EXP2(x) exp2f(x)
#endif
#else
#define EXP2(x) exp2f(x)
#endif

// ---------------- mask normalization (bool-byte vs int32 agnostic) -------------
__global__ __launch_bounds__(256) void normalize_mask_kernel(
    const unsigned char* __restrict__ raw, int* __restrict__ outm, int n) {
    __shared__ int s_isbyte;
    const int tid = threadIdx.x;
    if (tid == 0) s_isbyte = 0;
    __syncthreads();
    int found = 0;
    for (int i = tid; i < n; i += 256) {
        if ((i & 3) != 0 && raw[i] != 0) found = 1;
    }
    if (found) atomicOr(&s_isbyte, 1);
    __syncthreads();
    const int isbyte = s_isbyte;
    if (isbyte) {
        for (int i = tid; i < n; i += 256) outm[i] = raw[i] ? 1 : 0;
    } else {
        const int* r32 = (const int*)raw;
        for (int i = tid; i < n; i += 256) outm[i] = r32[i] ? 1 : 0;
    }
}

// ---------------- f32 -> f16 conversion (3 tensors, one launch) ----------------
__global__ __launch_bounds__(256) void cvt_all_f16(
    const float* __restrict__ in0, _Float16* __restrict__ out0, int n0,
    const float* __restrict__ in1, _Float16* __restrict__ out1, int n1,
    const float* __restrict__ in2, _Float16* __restrict__ out2, int n2) {
    int i = blockIdx.x * 256 + threadIdx.x;
    const float* in;
    _Float16* out;
    if (i < n0) { in = in0; out = out0; }
    else if (i < n0 + n1) { i -= n0; in = in1; out = out1; }
    else { i -= n0 + n1; in = in2; out = out2; if (i >= n2) return; }
    const float4 v = ((const float4*)in)[i];
    f16x4 o;
    o[0] = (_Float16)v.x; o[1] = (_Float16)v.y;
    o[2] = (_Float16)v.z; o[3] = (_Float16)v.w;
    ((f16x4*)out)[i] = o;
}

// ---------------- f16 MFMA GEMM: C[m,n] = sum_k A[m,k]*W[n,k] + bias[n] --------
// m97 structure: 128x128 tile, BK=64, global_load_lds(16B) staging, linear LDS
// with XOR-swizzle (col16 ^= row&7) applied on global source AND ds_read addr.
// 256 threads = 4 waves (2x2 of 64x64 wave tiles).
// MODE 0: write f32 out with rowmask zeroing.
// MODE 1: scatter f16 into q[B,H,S,64], k[B,H,S,64], vt[B,H,64,S].
template <int MODE>
__global__ __launch_bounds__(256) void gemm16(
    const _Float16* __restrict__ A, const _Float16* __restrict__ Wm,
    const float* __restrict__ bias, const int* __restrict__ rowmask,
    int K, int N, float* __restrict__ outf,
    _Float16* __restrict__ qb, _Float16* __restrict__ kb,
    _Float16* __restrict__ vtb) {
    __shared__ _Float16 As[128 * 64];   // 16 KB, row stride 64 halves (128 B)
    __shared__ _Float16 Bs[128 * 64];   // 16 KB
    const int bm = blockIdx.y * 128;
    const int bn = blockIdx.x * 128;
    const int tid = threadIdx.x;
    const int w = tid >> 6, l = tid & 63;
    const int wm = (w >> 1) * 64, wn = (w & 1) * 64;
    const int lg = l >> 4, lc = l & 15;

    // staging geometry: chunk ci covers rows [ci*8, ci*8+8), 1 KB per wave-instr
    const int srow_in = l >> 3;          // 0..7 row within chunk
    const int sc16 = l & 7;              // storage col16 slot

    f32x4 acc[4][4] = {};

    for (int kt = 0; kt < K; kt += 64) {
#pragma unroll
        for (int i = 0; i < 4; ++i) {
            const int ci = (w << 2) + i;          // 0..15
            const int r = (ci << 3) + srow_in;    // 0..127
            const int c16 = sc16 ^ (r & 7);       // inverse-swizzled source col
            const _Float16* gA = A + (size_t)(bm + r) * K + kt + c16 * 8;
            const _Float16* gB = Wm + (size_t)(bn + r) * K + kt + c16 * 8;
            __builtin_amdgcn_global_load_lds((as1_void*)gA,
                                             (as3_void*)(As + ci * 512), 16, 0, 0);
            __builtin_amdgcn_global_load_lds((as1_void*)gB,
                                             (as3_void*)(Bs + ci * 512), 16, 0, 0);
        }
        asm volatile("s_waitcnt vmcnt(0)" ::: "memory");
        __syncthreads();

#pragma unroll
        for (int kk = 0; kk < 2; ++kk) {
            f16x8 af[4], bf[4];
#pragma unroll
            for (int mi = 0; mi < 4; ++mi) {
                const int row = wm + mi * 16 + lc;
                const int c16 = ((kk << 2) + lg) ^ (lc & 7);
                af[mi] = *(const f16x8*)&As[row * 64 + c16 * 8];
            }
#pragma unroll
            for (int ni = 0; ni < 4; ++ni) {
                const int row = wn + ni * 16 + lc;
                const int c16 = ((kk << 2) + lg) ^ (lc & 7);
                bf[ni] = *(const f16x8*)&Bs[row * 64 + c16 * 8];
            }
#pragma unroll
            for (int mi = 0; mi < 4; ++mi)
#pragma unroll
                for (int ni = 0; ni < 4; ++ni)
                    acc[mi][ni] = __builtin_amdgcn_mfma_f32_16x16x32_f16(
                        af[mi], bf[ni], acc[mi][ni], 0, 0, 0);
        }
        __syncthreads();
    }

    if (MODE == 0) {
#pragma unroll
        for (int mi = 0; mi < 4; ++mi) {
#pragma unroll
            for (int j = 0; j < 4; ++j) {
                const int m = bm + wm + mi * 16 + lg * 4 + j;
                const int mv = rowmask[m];
#pragma unroll
                for (int ni = 0; ni < 4; ++ni) {
                    const int col = bn + wn + ni * 16 + lc;
                    outf[(size_t)m * N + col] =
                        mv ? acc[mi][ni][j] + bias[col] : 0.f;
                }
            }
        }
    } else {
#pragma unroll
        for (int ni = 0; ni < 4; ++ni) {
            const int col = bn + wn + ni * 16 + lc;
            const int which = col / 768;
            const int rem = col - which * 768;
            const int hh = rem >> 6, hd = rem & 63;
            const float bs = bias[col];
            const size_t hb = (size_t)hh;
#pragma unroll
            for (int mi = 0; mi < 4; ++mi) {
#pragma unroll
                for (int j = 0; j < 4; ++j) {
                    const int m = bm + wm + mi * 16 + lg * 4 + j;
                    const int b_ = m >> 10, s_ = m & 1023;
                    const _Float16 val = (_Float16)(acc[mi][ni][j] + bs);
                    const size_t bhh = (size_t)(b_ * H) + hb;
                    if (which == 0)
                        qb[(bhh * S + s_) * HD + hd] = val;
                    else if (which == 1)
                        kb[(bhh * S + s_) * HD + hd] = val;
                    else
                        vtb[(bhh * HD + hd) * S + s_] = val;
                }
            }
        }
    }
}

// ---------------- flash attention, f16 MFMA, fixed-max softmax -----------------
// grid: B*H*(S/64); block 256 = 4 waves; wave w owns q-rows [qt*64+w*16, +16).
// 64-key tiles; K,Vt staged in LDS (shared by 4 waves) with async-stage split.
__global__ __launch_bounds__(256) void attn_kernel(
    const _Float16* __restrict__ qb, const _Float16* __restrict__ kb,
    const _Float16* __restrict__ vtb, const int* __restrict__ mask,
    _Float16* __restrict__ ctx) {
    __shared__ _Float16 ksm[64][72];   // [key][hd], padded
    __shared__ _Float16 vsm[64][72];   // [hd-d][key], padded (from Vt)
    __shared__ _Float16 pl[4][16][72]; // per-wave P: [q-row][key]
    __shared__ int kml[64];

    const int blk = blockIdx.x;
    const int qt = blk & 15;
    const int h = (blk >> 4) % H;
    const int b = blk / (16 * H);
    const int tid = threadIdx.x;
    const int w = tid >> 6, lane = tid & 63;
    const int lg = lane >> 4, lc = lane & 15;

    const size_t bh = (size_t)(b * H + h);
    const _Float16* Kp = kb + bh * S * HD;
    const _Float16* Vt = vtb + bh * HD * S;
    const int* mrow = mask + b * S;

    const int srow = tid >> 3;          // 0..31
    const int scol = (tid & 7) * 8;     // 0,8,..,56

    // Q fragment (A-frag row = lc), pre-scaled by SCALE*log2(e)
    const int qrow_frag = qt * 64 + w * 16 + lc;
    const _Float16* Qp = qb + (bh * S + qrow_frag) * HD;
    f16x8 qf0 = *(const f16x8*)(Qp + lg * 8);
    f16x8 qf1 = *(const f16x8*)(Qp + 32 + lg * 8);
    const _Float16 qs = (_Float16)(0.125f * 1.44269504f);
    qf0 *= qs; qf1 *= qs;

    // prologue: stage tile 0
    *(f16x8*)&ksm[srow][scol]      = *(const f16x8*)(Kp + (size_t)srow * HD + scol);
    *(f16x8*)&ksm[32 + srow][scol] = *(const f16x8*)(Kp + (size_t)(32 + srow) * HD + scol);
    *(f16x8*)&vsm[srow][scol]      = *(const f16x8*)(Vt + (size_t)srow * S + scol);
    *(f16x8*)&vsm[32 + srow][scol] = *(const f16x8*)(Vt + (size_t)(32 + srow) * S + scol);
    if (tid < 64) kml[tid] = mrow[tid];
    __syncthreads();

    f32x4 acc[4] = {};
    float l_part[4] = {0.f, 0.f, 0.f, 0.f};

    for (int it = 0; it < S / 64; ++it) {
        const int ktn = (it + 1) * 64;
        const bool pref = (it + 1 < S / 64);
        f16x8 gk0, gk1, gv0, gv1;
        int kmn = 0;
        if (pref) {  // issue next tile's loads early (hide under compute)
            gk0 = *(const f16x8*)(Kp + (size_t)(ktn + srow) * HD + scol);
            gk1 = *(const f16x8*)(Kp + (size_t)(ktn + 32 + srow) * HD + scol);
            gv0 = *(const f16x8*)(Vt + (size_t)srow * S + ktn + scol);
            gv1 = *(const f16x8*)(Vt + (size_t)(32 + srow) * S + ktn + scol);
            if (tid < 64) kmn = mrow[ktn + tid];
        }

        // QK^T: 16q x 64k (K=64 contraction via 2 MFMA per key-group)
        f32x4 cs[4];
#pragma unroll
        for (int t = 0; t < 4; ++t) {
            const f16x8 kfa = *(const f16x8*)&ksm[t * 16 + lc][lg * 8];
            const f16x8 kfb = *(const f16x8*)&ksm[t * 16 + lc][32 + lg * 8];
            f32x4 c = {};
            c = __builtin_amdgcn_mfma_f32_16x16x32_f16(qf0, kfa, c, 0, 0, 0);
            c = __builtin_amdgcn_mfma_f32_16x16x32_f16(qf1, kfb, c, 0, 0, 0);
            cs[t] = c;
        }

        // fixed-max softmax: p = exp2(qk*SCALE*log2e - C2); lane-local l sums
#pragma unroll
        for (int t = 0; t < 4; ++t) {
            const int kv = kml[t * 16 + lc];
#pragma unroll
            for (int j = 0; j < 4; ++j) {
                const float p = kv ? EXP2(cs[t][j] - C2) : 0.f;
                l_part[j] += p;
                pl[w][lg * 4 + j][t * 16 + lc] = (_Float16)p;
            }
        }

        // PV: P[16x64] x V^T-frags (contraction over keys, 2 chunks of 32)
        const f16x8 pf0 = *(const f16x8*)&pl[w][lc][lg * 8];
        const f16x8 pf1 = *(const f16x8*)&pl[w][lc][32 + lg * 8];
#pragma unroll
        for (int t = 0; t < 4; ++t) {
            const f16x8 vfa = *(const f16x8*)&vsm[t * 16 + lc][lg * 8];
            const f16x8 vfb = *(const f16x8*)&vsm[t * 16 + lc][32 + lg * 8];
            acc[t] = __builtin_amdgcn_mfma_f32_16x16x32_f16(pf0, vfa, acc[t], 0, 0, 0);
            acc[t] = __builtin_amdgcn_mfma_f32_16x16x32_f16(pf1, vfb, acc[t], 0, 0, 0);
        }

        __syncthreads();   // all waves done reading ksm/vsm
        if (pref) {
            *(f16x8*)&ksm[srow][scol] = gk0;
            *(f16x8*)&ksm[32 + srow][scol] = gk1;
            *(f16x8*)&vsm[srow][scol] = gv0;
            *(f16x8*)&vsm[32 + srow][scol] = gv1;
            if (tid < 64) kml[tid] = kmn;
            __syncthreads();
        }
    }

    // epilogue: reduce l across the 16 key-lanes, normalize, write
#pragma unroll
    for (int j = 0; j < 4; ++j) {
        float l = l_part[j];
        l += __shfl_xor(l, 1);
        l += __shfl_xor(l, 2);
        l += __shfl_xor(l, 4);
        l += __shfl_xor(l, 8);
        const int qr = qt * 64 + w * 16 + lg * 4 + j;
        const int qv = mrow[qr];
        const float inv = (qv && l > 0.f) ? 1.f / l : 0.f;
        const size_t o = ((size_t)(b * S + qr)) * D + h * HD;
#pragma unroll
        for (int t = 0; t < 4; ++t)
            ctx[o + 16 * t + lc] = (_Float16)(acc[t][j] * inv);
    }
}

// -------------------------------------------------------------------------------
extern "C" void kernel_launch(void* const* d_in, const int* in_sizes, int n_in,
                              void* d_out, int out_size, void* d_ws, size_t ws_size,
                              hipStream_t stream) {
    const float* hidden = (const float*)d_in[0];
    const unsigned char* maskraw = (const unsigned char*)d_in[1];
    const float* qkv_w = (const float*)d_in[2];
    const float* qkv_b = (const float*)d_in[3];
    const float* proj_w = (const float*)d_in[4];
    const float* proj_b = (const float*)d_in[5];
    float* out = (float*)d_out;

    char* ws = (char*)d_ws;
    size_t off = 0;
    int* maskN = (int*)(ws + off);          off += (size_t)NTOK * 4;
    _Float16* hid16 = (_Float16*)(ws + off); off += (size_t)NTOK * D * 2;
    _Float16* qkvw16 = (_Float16*)(ws + off); off += (size_t)QKV_N * D * 2;
    _Float16* projw16 = (_Float16*)(ws + off); off += (size_t)D * D * 2;
    _Float16* qb = (_Float16*)(ws + off);   off += (size_t)NTOK * D * 2;
    _Float16* kbuf = (_Float16*)(ws + off); off += (size_t)NTOK * D * 2;
    _Float16* vtb = (_Float16*)(ws + off);  off += (size_t)NTOK * D * 2;
    _Float16* ctx16 = (_Float16*)(ws + off); off += (size_t)NTOK * D * 2;

    normalize_mask_kernel<<<1, 256, 0, stream>>>(maskraw, maskN, NTOK);

    const int n0 = NTOK * D / 4, n1 = QKV_N * D / 4, n2 = D * D / 4;
    cvt_all_f16<<<(n0 + n1 + n2 + 255) / 256, 256, 0, stream>>>(
        hidden, hid16, n0, qkv_w, qkvw16, n1, proj_w, projw16, n2);

    dim3 g1(QKV_N / 128, NTOK / 128);   // (18, 128)
    gemm16<1><<<g1, 256, 0, stream>>>(hid16, qkvw16, qkv_b, nullptr,
                                      D, QKV_N, nullptr, qb, kbuf, vtb);

    attn_kernel<<<dim3(B * H * (S / 64)), 256, 0, stream>>>(qb, kbuf, vtb, maskN, ctx16);

    dim3 g2(D / 128, NTOK / 128);       // (6, 128)
    gemm16<0><<<g2, 256, 0, stream>>>(ctx16, projw16, proj_b, maskN,
                                      D, D, out, nullptr, nullptr, nullptr);
}